// Round 6
// baseline (388.302 us; speedup 1.0000x reference)
//
#include <hip/hip_runtime.h>

// ScaledDotProductAttention: B=4, NQ=NK=2048, D_MODEL=D_K=D_V=1024, H=16, HD=64.
// Full bf16-MFMA pipeline (fp32 accumulate everywhere):
//  1) transpose_cast_w : W* fp32 [K][N] -> bf16 [N][K]   (B^T layout for MFMA B-frags)
//  2) proj_kernel      : Q/K/V projections, 128x128 tile, BK=32.
//                        R11: R10's counted-vmcnt pipeline was a NULL (166us == R9):
//                        the C++ ds_reads alias the gload_lds-written LDS, so the
//                        compiler inserted its own `s_waitcnt vmcnt(0)` before them,
//                        draining the just-issued stage(t+2) every step (full latency
//                        exposed; MfmaUtil 12%). Now ALL in-loop LDS reads are
//                        inline-asm ds_read_b128 (opaque to alias analysis) with
//                        explicit lgkmcnt(0)+sched_barrier(0) (rule #18); the only
//                        waits are OUR counted vmcnt(6) before the raw s_barrier.
//                        3 buffers, 2-deep prefetch, tail drains 6->0.
//  3) attn_kernel      : transposed-S flash attention (R7 LDS staging + R8 (256,2);
//                        unchanged -- per-tile compute covers its 1-deep drain).
//  4) out_kernel       : O @ Wo + bo. R11: same asm-read counted-vmcnt template
//                        (S=4 -> vmcnt(4)).
// Workspace: 72 MiB total (offsets below, unchanged).

#define DM    1024
#define NSEQ  2048
#define HEADS 16
#define HD    64

typedef float floatx4 __attribute__((ext_vector_type(4)));
typedef short s16x4   __attribute__((ext_vector_type(4)));
typedef short s16x8   __attribute__((ext_vector_type(8)));
typedef unsigned int u32x4 __attribute__((ext_vector_type(4)));

static __device__ __forceinline__ floatx4 mfma_bf16(s16x8 a, s16x8 b, floatx4 c) {
  return __builtin_amdgcn_mfma_f32_16x16x32_bf16(a, b, c, 0, 0, 0);
}

// Async global->LDS DMA, 16B per lane: dest = wave-uniform base + lane*16,
// source = per-lane global address.
static __device__ __forceinline__ void gload_lds16(const void* g, void* l) {
  __builtin_amdgcn_global_load_lds(
      (const __attribute__((address_space(1))) unsigned*)g,
      (__attribute__((address_space(3))) unsigned*)l, 16, 0, 0);
}

// 32-bit LDS byte address from a generic pointer into __shared__ (low 32 bits
// of the generic address ARE the LDS offset on gfx9+).
static __device__ __forceinline__ unsigned lds_addr(const void* p) {
  return (unsigned)(unsigned long long)p;
}

// Inline-asm ds_read_b128: invisible to alias analysis, so the compiler cannot
// attach a vmcnt(0) drain for the global_load_lds writes. Caller MUST follow a
// read batch with s_waitcnt lgkmcnt(0) + sched_barrier(0) (rule #18).
static __device__ __forceinline__ s16x8 ds_read_b128a(unsigned byteaddr) {
  s16x8 r;
  asm volatile("ds_read_b128 %0, %1" : "=v"(r) : "v"(byteaddr));
  return r;
}

#define WAIT_LGKM0() \
  { asm volatile("s_waitcnt lgkmcnt(0)" ::: "memory"); __builtin_amdgcn_sched_barrier(0); }
#define WAIT_VMCNT(N) asm volatile("s_waitcnt vmcnt(" #N ")" ::: "memory")

// fp32 -> bf16 round-to-nearest-even (bit trick; inputs are finite)
static __device__ __forceinline__ short f2bf(float f) {
  unsigned u = __builtin_bit_cast(unsigned, f);
  u += 0x7FFFu + ((u >> 16) & 1u);
  return (short)(u >> 16);
}

// Packed fp32 pair -> 2 bf16 (RNE, same result as f2bf) in one VALU op.
static __device__ __forceinline__ unsigned cvtpk_bf16(float lo, float hi) {
  unsigned r;
  asm("v_cvt_pk_bf16_f32 %0, %1, %2" : "=v"(r) : "v"(lo), "v"(hi));
  return r;
}

// Pack 2 fp32 -> 2 bf16 in one u32 (round-half-up: +0x8000, keep high halves).
static __device__ __forceinline__ unsigned pack2_bf16(float a, float b) {
  unsigned ua = __builtin_bit_cast(unsigned, a) + 0x8000u;
  unsigned ub = __builtin_bit_cast(unsigned, b) + 0x8000u;
#if __has_builtin(__builtin_amdgcn_perm)
  return __builtin_amdgcn_perm(ub, ua, 0x07060302u);  // lo=hi16(ua), hi=hi16(ub)
#else
  return (ub & 0xffff0000u) | (ua >> 16);
#endif
}

// ---------------------------------------------------------------------------
// 1) Weight transpose + cast: W [1024 k][1024 n] fp32 -> Wt [n][k] bf16
__global__ __launch_bounds__(256) void transpose_cast_w(
    const float* __restrict__ W0, const float* __restrict__ W1,
    const float* __restrict__ W2, const float* __restrict__ W3,
    short* __restrict__ T0, short* __restrict__ T1,
    short* __restrict__ T2, short* __restrict__ T3) {
  __shared__ float tile[32][33];
  const float* W = blockIdx.z == 0 ? W0 : blockIdx.z == 1 ? W1 : blockIdx.z == 2 ? W2 : W3;
  short*       T = blockIdx.z == 0 ? T0 : blockIdx.z == 1 ? T1 : blockIdx.z == 2 ? T2 : T3;
  const int bx = blockIdx.x * 32;  // n-offset
  const int by = blockIdx.y * 32;  // k-offset
  const int tx = threadIdx.x, ty = threadIdx.y;
  for (int i = 0; i < 4; i++)
    tile[ty + i * 8][tx] = W[(long)(by + ty + i * 8) * DM + bx + tx];
  __syncthreads();
  for (int i = 0; i < 4; i++)
    T[(long)(bx + ty + i * 8) * DM + by + tx] = f2bf(tile[tx][ty + i * 8]);
}

// ---------------------------------------------------------------------------
// 2) Projection GEMM: C[8192x1024] = A(fp32) @ W.
//    Per 24KiB buffer: A fp32 fragment-major, 16 groups x 1KiB at byte g*1024:
//      g=(g16,h): chunk l holds A[row0+g16*16+(l&15)][k0 + (l>>4)*8 + h*4 ..+4] fp32.
//    B bf16, 8 groups x 1KiB at byte 16384 + gb*1024:
//      chunk l holds Bt[col0+gb*16+(l&15)][k0 + (l>>4)*8 ..+8].
//    Consumer (lane l): af[mi] = cvt_pk of groups (wm*4+mi)*2{,+1}; bfr[ni] =
//    group wn*4+ni; all at group_base + l*16: linear, conflict-free.
//    z=0: queries->Qh (PRE-SCALED log2e/sqrt(1024)), 1: keys->Kh, 2: values->Vt.
__global__ __launch_bounds__(256, 2) void proj_kernel(
    const float* __restrict__ Aq, const float* __restrict__ Ak, const float* __restrict__ Av,
    const short* __restrict__ BtQ, const short* __restrict__ BtK, const short* __restrict__ BtV,
    short* __restrict__ Qh, short* __restrict__ Kh, short* __restrict__ Vt) {
  __shared__ short lds[3 * 12288];  // 3 x 24KiB (A 16KiB fp32 + B 8KiB bf16)
  const int z = blockIdx.z;
  const float* A  = z == 0 ? Aq  : z == 1 ? Ak  : Av;
  const short* Bt = z == 0 ? BtQ : z == 1 ? BtK : BtV;
  const int t = threadIdx.x;
  const int w = t >> 6, l = t & 63, quad = l >> 4, lm = l & 15;
  const int wm = w >> 1, wn = w & 1;
  const int row0 = blockIdx.x * 128, col0 = blockIdx.y * 128;

  floatx4 acc[4][4];
  for (int mi = 0; mi < 4; mi++)
    for (int ni = 0; ni < 4; ni++) acc[mi][ni] = (floatx4){0.f, 0.f, 0.f, 0.f};

  // Stage tile k0 into buffer buf. Wave w: A groups w*4..w*4+3, B groups w*2,w*2+1.
  // 6 gload_lds per wave per stage (= the vmcnt count).
  auto stage = [&](int k0, int buf) __attribute__((always_inline)) {
    short* base = lds + buf * 12288;
#pragma unroll
    for (int i = 0; i < 4; i++) {
      int g = w * 4 + i;
      const float* src =
          A + (long)(row0 + ((g >> 1) << 4) + lm) * DM + k0 + quad * 8 + (g & 1) * 4;
      gload_lds16(src, base + g * 512);
    }
#pragma unroll
    for (int i = 0; i < 2; i++) {
      int gb = w * 2 + i;
      const short* src = Bt + (long)(col0 + gb * 16 + lm) * DM + k0 + quad * 8;
      gload_lds16(src, base + 8192 + gb * 512);
    }
  };

  const unsigned lds0 = lds_addr(lds);
  auto process = [&](int buf) __attribute__((always_inline)) {
    const unsigned lbase = lds0 + buf * 24576;
    const unsigned abase = lbase + wm * 8192 + l * 16;
    const unsigned bbase = lbase + 16384 + wn * 4096 + l * 16;
    floatx4 alo[4], ahi[4];
    s16x8 bfr[4];
#pragma unroll
    for (int mi = 0; mi < 4; mi++) {
      alo[mi] = __builtin_bit_cast(floatx4, ds_read_b128a(abase + (mi * 2) * 1024));
      ahi[mi] = __builtin_bit_cast(floatx4, ds_read_b128a(abase + (mi * 2 + 1) * 1024));
    }
#pragma unroll
    for (int ni = 0; ni < 4; ni++)
      bfr[ni] = ds_read_b128a(bbase + ni * 1024);
    WAIT_LGKM0();  // asm reads done; fence so MFMAs can't hoist above (rule #18)
    s16x8 af[4];
#pragma unroll
    for (int mi = 0; mi < 4; mi++) {
      u32x4 p = {cvtpk_bf16(alo[mi][0], alo[mi][1]), cvtpk_bf16(alo[mi][2], alo[mi][3]),
                 cvtpk_bf16(ahi[mi][0], ahi[mi][1]), cvtpk_bf16(ahi[mi][2], ahi[mi][3])};
      af[mi] = __builtin_bit_cast(s16x8, p);
    }
    __builtin_amdgcn_s_setprio(1);
#pragma unroll
    for (int mi = 0; mi < 4; mi++)
#pragma unroll
      for (int ni = 0; ni < 4; ni++)
        acc[mi][ni] = mfma_bf16(af[mi], bfr[ni], acc[mi][ni]);
    __builtin_amdgcn_s_setprio(0);
  };

  // 2-deep prefetch; per step: wait for the OLDER stage only (newest stays in
  // flight across the raw barrier), then stage t+2 and compute t.
  stage(0, 0);
  stage(32, 1);
  int cur = 0;                    // t % 3
  for (int tt = 0; tt < 30; ++tt) {
    WAIT_VMCNT(6);                // stage(t) landed; stage(t+1)'s 6 may be in flight
    __builtin_amdgcn_s_barrier();
    __builtin_amdgcn_sched_barrier(0);
    int nb = cur + 2 >= 3 ? cur - 1 : cur + 2;  // (t+2)%3
    stage((tt + 2) * 32, nb);
    __builtin_amdgcn_sched_barrier(0);
    process(cur);
    cur = cur + 1 >= 3 ? 0 : cur + 1;
  }
  WAIT_VMCNT(6);                  // t=30: stage(31) may be in flight, stage(30) done
  __builtin_amdgcn_s_barrier();
  __builtin_amdgcn_sched_barrier(0);
  process(cur);                   // buffer 30%3 = 0
  cur = cur + 1 >= 3 ? 0 : cur + 1;
  WAIT_VMCNT(0);                  // t=31: full drain (also safe for kernel exit)
  __builtin_amdgcn_s_barrier();
  __builtin_amdgcn_sched_barrier(0);
  process(cur);                   // buffer 31%3 = 1

  const int rowbase = row0 + wm * 64;  // multiple of 64 -> single b per wave
  const int colbase = col0 + wn * 64;  // multiple of 64 -> single head per wave
  const int b = rowbase >> 11;
  const int h = colbase >> 6;
  const int rloc = rowbase & 2047;
  if (z < 2) {
    short* Out = z == 0 ? Qh : Kh;
    // Fold softmax scale * log2(e) into Q so attn uses exp2 with no multiply.
    const float osc = z == 0 ? 0.0450842200277801f : 1.0f;
    long base = ((long)(b * HEADS + h)) * NSEQ * HD;
    for (int mi = 0; mi < 4; mi++)
      for (int r = 0; r < 4; r++) {
        int q = rloc + mi * 16 + quad * 4 + r;
        long rowoff = base + (long)q * HD + lm;
        for (int ni = 0; ni < 4; ni++)
          Out[rowoff + ni * 16] = f2bf(acc[mi][ni][r] * osc);
      }
  } else {
    // Vt with per-32-key interleave: key kloc=(j*16+quad*4+r) within its 32-group
    // is stored at position quad*8 + j*4 + r, so attn reads one 16B chunk per
    // (d-row, quad) covering a full K=32 logical-k fragment.
    long base = ((long)(b * HEADS + h)) * HD * NSEQ;
    for (int mi = 0; mi < 4; mi++)
      for (int r = 0; r < 4; r++) {
        int kcol = rloc + (mi >> 1) * 32 + quad * 8 + (mi & 1) * 4 + r;
        for (int ni = 0; ni < 4; ni++)
          Vt[base + (long)(ni * 16 + lm) * NSEQ + kcol] = f2bf(acc[mi][ni][r]);
      }
  }
}

// ---------------------------------------------------------------------------
// 3) Transposed-S flash attention. Grid (bh=64, qy=16) -> XCD = bh%8 (L2 local).
//    4 waves/block, wave = 32 q-rows (2x16); K/V tile (64 keys) staged ONCE per
//    block in LDS, fragment-major (16 groups x 1KiB), global_load_lds, double-
//    buffered T3 2-phase. (256,2): 256-VGPR class, no spill (R8). Unchanged:
//    its per-tile compute (~1200cy) covers the 1-deep issue-early drain.
__global__ __launch_bounds__(256, 2) void attn_kernel(
    const short* __restrict__ Qh, const short* __restrict__ Kh,
    const short* __restrict__ Vt, short* __restrict__ Obf) {
  __shared__ short lds[2 * 8192];  // 2 x 16KiB tile buffers; epilogue reuses buf0
  const int t = threadIdx.x;
  const int w = t >> 6, l = t & 63, quad = l >> 4, lm = l & 15;
  const int bh = blockIdx.x;    // b*16+h  (grid-x => XCD = bh%8: L2 locality)
  const int qtile = blockIdx.y * 128 + w * 32;
  const short* Qp = Qh + (long)bh * NSEQ * HD;
  const short* Kp = Kh + (long)bh * NSEQ * HD;
  const short* Vp = Vt + (long)bh * HD * NSEQ;

  s16x8 aq[2][2];  // Q-frags; serve as MFMA *B* operand for S^T (layout identical)
#pragma unroll
  for (int qi = 0; qi < 2; qi++)
#pragma unroll
    for (int c = 0; c < 2; c++)
      aq[qi][c] = *(const s16x8*)(Qp + (long)(qtile + qi * 16 + lm) * HD + c * 32 + quad * 8);

  floatx4 acc[2][4];  // O^T, C-layout: d = n*16+quad*4+reg, q = lm
  float lsum[2] = {0.f, 0.f};
#pragma unroll
  for (int qi = 0; qi < 2; qi++)
#pragma unroll
    for (int n = 0; n < 4; n++) acc[qi][n] = (floatx4){0.f, 0.f, 0.f, 0.f};

  // Stage the 64-key tile at kt into buffer `buf`. Wave w stages groups 4w..4w+3.
  auto stage = [&](int kt, int buf) __attribute__((always_inline)) {
    short* base = lds + buf * 8192;
#pragma unroll
    for (int i = 0; i < 4; i++) {
      int g = w * 4 + i;
      const short* src;
      if (w < 2) {  // K groups 0..7
        int s = (g >> 2) & 1, j = (g >> 1) & 1, c = g & 1;
        src = Kp + (long)(kt + s * 32 + j * 16 + lm) * HD + c * 32 + quad * 8;
      } else {      // V groups 8..15
        int gg = g & 7;
        int s = gg >> 2, n = gg & 3;
        src = Vp + (long)(n * 16 + lm) * NSEQ + kt + s * 32 + quad * 8;
      }
      gload_lds16(src, base + g * 512);
    }
  };

  // Process one 32-key subtile (s = 0/1) from tile buffer Lb.
  auto process = [&](const short* Lb, int s) __attribute__((always_inline)) {
    s16x8 bk[2][2];
#pragma unroll
    for (int j = 0; j < 2; j++)
#pragma unroll
      for (int c = 0; c < 2; c++)
        bk[j][c] = *(const s16x8*)(Lb + ((s * 4 + j * 2 + c) * 64 + l) * 8);
    s16x8 vraw[4];
#pragma unroll
    for (int n = 0; n < 4; n++)
      vraw[n] = *(const s16x8*)(Lb + ((8 + s * 4 + n) * 64 + l) * 8);
#pragma unroll
    for (int qi = 0; qi < 2; qi++) {
      floatx4 sT[2];
      sT[0] = (floatx4){0.f, 0.f, 0.f, 0.f};
      sT[1] = (floatx4){0.f, 0.f, 0.f, 0.f};
      __builtin_amdgcn_s_setprio(1);
#pragma unroll
      for (int c = 0; c < 2; c++) {
        sT[0] = mfma_bf16(bk[0][c], aq[qi][c], sT[0]);
        sT[1] = mfma_bf16(bk[1][c], aq[qi][c], sT[1]);
      }
      __builtin_amdgcn_s_setprio(0);
      float p0 = __builtin_amdgcn_exp2f(sT[0][0]);
      float p1 = __builtin_amdgcn_exp2f(sT[0][1]);
      float p2 = __builtin_amdgcn_exp2f(sT[0][2]);
      float p3 = __builtin_amdgcn_exp2f(sT[0][3]);
      float p4 = __builtin_amdgcn_exp2f(sT[1][0]);
      float p5 = __builtin_amdgcn_exp2f(sT[1][1]);
      float p6 = __builtin_amdgcn_exp2f(sT[1][2]);
      float p7 = __builtin_amdgcn_exp2f(sT[1][3]);
      lsum[qi] += ((p0 + p1) + (p2 + p3)) + ((p4 + p5) + (p6 + p7));
      u32x4 pw = {pack2_bf16(p0, p1), pack2_bf16(p2, p3),
                  pack2_bf16(p4, p5), pack2_bf16(p6, p7)};
      s16x8 pcat = __builtin_bit_cast(s16x8, pw);
      __builtin_amdgcn_s_setprio(1);
#pragma unroll
      for (int n = 0; n < 4; n++)
        acc[qi][n] = mfma_bf16(vraw[n], pcat, acc[qi][n]);
      __builtin_amdgcn_s_setprio(0);
    }
  };

  stage(0, 0);
  __syncthreads();  // compiler-emitted vmcnt(0) drain + s_barrier: tile 0 ready
  int cur = 0;
  for (int kt = 0; kt < NSEQ; kt += 64) {
    if (kt + 64 < NSEQ) stage(kt + 64, cur ^ 1);  // issue DMA, then compute
    const short* Lb = lds + cur * 8192;
    process(Lb, 0);
    process(Lb, 1);
    __syncthreads();  // drain (hidden under process) + cross-wave visibility
    cur ^= 1;
  }

  // lsum is per-lane over this lane's keys; full row sum = reduce across quads.
  const int b = bh >> 4, h = bh & 15;
  short* Ow = lds + w * 1152;  // reuse buf0 (final iter read buf1; regions disjoint)
  const int erow = l >> 2, ecg = l & 3;  // epilogue read/store mapping
#pragma unroll
  for (int qi = 0; qi < 2; qi++) {
    float ls = lsum[qi];
    ls += __shfl_xor(ls, 16);
    ls += __shfl_xor(ls, 32);
    float rl = 1.0f / ls;  // row sum for q = lm (same for all regs)
#pragma unroll
    for (int n = 0; n < 4; n++)
#pragma unroll
      for (int r = 0; r < 4; r++)
        Ow[lm * 72 + n * 16 + quad * 4 + r] = f2bf(acc[qi][n][r] * rl);
    // read back row-major (same wave; compiler inserts lgkmcnt wait), store coalesced
    s16x8 o0 = *(const s16x8*)(Ow + erow * 72 + ecg * 16);
    s16x8 o1 = *(const s16x8*)(Ow + erow * 72 + ecg * 16 + 8);
    long gaddr = ((long)(b * NSEQ + qtile + qi * 16 + erow)) * DM + h * HD + ecg * 16;
    *(s16x8*)(Obf + gaddr) = o0;
    *(s16x8*)(Obf + gaddr + 8) = o1;
  }
}

// ---------------------------------------------------------------------------
// 4) Output GEMM: d_out = Obf(bf16) @ WoT + bo, fp32 out.
//    R11: asm-read counted-vmcnt 3-buffer template (S=4 -> vmcnt(4)), 16KiB/buf.
//    Groups 0..7 = A rows (byte g*1024), 8..15 = B rows (byte 8192+g*1024).
__global__ __launch_bounds__(256, 2) void out_kernel(
    const short* __restrict__ Ab, const short* __restrict__ Bt,
    const float* __restrict__ bias, float* __restrict__ Out) {
  __shared__ short lds[3 * 8192];
  const int t = threadIdx.x;
  const int w = t >> 6, l = t & 63, quad = l >> 4, lm = l & 15;
  const int wm = w >> 1, wn = w & 1;
  const int row0 = blockIdx.x * 128, col0 = blockIdx.y * 128;

  floatx4 acc[4][4];
  for (int mi = 0; mi < 4; mi++)
    for (int ni = 0; ni < 4; ni++) acc[mi][ni] = (floatx4){0.f, 0.f, 0.f, 0.f};

  auto stage = [&](int k0, int buf) __attribute__((always_inline)) {
    short* base = lds + buf * 8192;
#pragma unroll
    for (int i = 0; i < 4; i++) {
      int g = w * 4 + i;  // 0..15; wave-uniform branch
      const short* src = (g < 8)
          ? Ab + (long)(row0 + g * 16 + lm) * DM + k0 + quad * 8
          : Bt + (long)(col0 + (g - 8) * 16 + lm) * DM + k0 + quad * 8;
      gload_lds16(src, base + g * 512);
    }
  };
  const unsigned lds0 = lds_addr(lds);
  auto process = [&](int buf) __attribute__((always_inline)) {
    const unsigned lbase = lds0 + buf * 16384;
    const unsigned abase = lbase + wm * 4096 + l * 16;
    const unsigned bbase = lbase + 8192 + wn * 4096 + l * 16;
    s16x8 af[4], bfr[4];
#pragma unroll
    for (int mi = 0; mi < 4; mi++)
      af[mi] = ds_read_b128a(abase + mi * 1024);
#pragma unroll
    for (int ni = 0; ni < 4; ni++)
      bfr[ni] = ds_read_b128a(bbase + ni * 1024);
    WAIT_LGKM0();
    __builtin_amdgcn_s_setprio(1);
#pragma unroll
    for (int mi = 0; mi < 4; mi++)
#pragma unroll
      for (int ni = 0; ni < 4; ni++)
        acc[mi][ni] = mfma_bf16(af[mi], bfr[ni], acc[mi][ni]);
    __builtin_amdgcn_s_setprio(0);
  };

  stage(0, 0);
  stage(32, 1);
  int cur = 0;
  for (int tt = 0; tt < 30; ++tt) {
    WAIT_VMCNT(4);
    __builtin_amdgcn_s_barrier();
    __builtin_amdgcn_sched_barrier(0);
    int nb = cur + 2 >= 3 ? cur - 1 : cur + 2;
    stage((tt + 2) * 32, nb);
    __builtin_amdgcn_sched_barrier(0);
    process(cur);
    cur = cur + 1 >= 3 ? 0 : cur + 1;
  }
  WAIT_VMCNT(4);
  __builtin_amdgcn_s_barrier();
  __builtin_amdgcn_sched_barrier(0);
  process(cur);
  cur = cur + 1 >= 3 ? 0 : cur + 1;
  WAIT_VMCNT(0);
  __builtin_amdgcn_s_barrier();
  __builtin_amdgcn_sched_barrier(0);
  process(cur);

  const int rowbase = row0 + wm * 64;
  const int colbase = col0 + wn * 64;
  for (int mi = 0; mi < 4; mi++)
    for (int r = 0; r < 4; r++) {
      int gr = rowbase + mi * 16 + quad * 4 + r;
      for (int ni = 0; ni < 4; ni++) {
        int gc = colbase + ni * 16 + lm;
        Out[(long)gr * DM + gc] = acc[mi][ni][r] + bias[gc];
      }
    }
}

// ---------------------------------------------------------------------------
extern "C" void kernel_launch(void* const* d_in, const int* in_sizes, int n_in,
                              void* d_out, int out_size, void* d_ws, size_t ws_size,
                              hipStream_t stream) {
  (void)in_sizes; (void)n_in; (void)out_size; (void)ws_size;
  const float* queries = (const float*)d_in[0];
  const float* keys    = (const float*)d_in[1];
  const float* values  = (const float*)d_in[2];
  const float* Wq = (const float*)d_in[3];
  const float* Wk = (const float*)d_in[4];
  const float* Wv = (const float*)d_in[5];
  const float* Wo = (const float*)d_in[6];
  const float* bo = (const float*)d_in[7];
  float* out = (float*)d_out;

  char* ws = (char*)d_ws;
  const size_t MB = 1024 * 1024;
  short* WqT = (short*)(ws + 0 * MB);   // 2 MiB each
  short* WkT = (short*)(ws + 2 * MB);
  short* WvT = (short*)(ws + 4 * MB);
  short* WoT = (short*)(ws + 6 * MB);
  short* Qh  = (short*)(ws + 8 * MB);   // [B,H,2048,64] bf16 = 16 MiB
  short* Kh  = (short*)(ws + 24 * MB);  // 16 MiB
  short* Vt  = (short*)(ws + 40 * MB);  // [B,H,64,2048] bf16 (interleaved cols) = 16 MiB
  short* Obf = (short*)(ws + 56 * MB);  // [8192,1024] bf16 = 16 MiB  (total 72 MiB)

  transpose_cast_w<<<dim3(32, 32, 4), dim3(32, 8), 0, stream>>>(
      Wq, Wk, Wv, Wo, WqT, WkT, WvT, WoT);
  proj_kernel<<<dim3(64, 8, 3), 256, 0, stream>>>(
      queries, keys, values, WqT, WkT, WvT, Qh, Kh, Vt);
  attn_kernel<<<dim3(64, 16), 256, 0, stream>>>(Qh, Kh, Vt, Obf);
  out_kernel<<<dim3(64, 8), 256, 0, stream>>>(Obf, WoT, bo, out);
}

// Round 7
// 370.016 us; speedup vs baseline: 1.0494x; 1.0494x over previous
//
#include <hip/hip_runtime.h>

// ScaledDotProductAttention: B=4, NQ=NK=2048, D_MODEL=D_K=D_V=1024, H=16, HD=64.
// Full bf16-MFMA pipeline (fp32 accumulate everywhere):
//  1) transpose_cast_w : W* fp32 [K][N] -> bf16 [N][K]   (B^T layout for MFMA B-frags)
//  2) proj_kernel      : Q/K/V projections.
//                        R12: 128x256 tile, 512 thr (8 waves 2x4, 64x64/wave), BK=32.
//                        WHY: R9/R10/R11 all measured 166us across three different
//                        sync structures -> scheduling-invariant. Staged operand
//                        traffic = 1.18GB @ ~7.1 TB/s (L3/fabric ceiling; FETCH is
//                        compulsory-only, HBM 12%). Only lever is arithmetic
//                        intensity: 128x256 tile cuts traffic to 768MB (-35%) and
//                        halves LDS -> 2 blocks/CU (16 waves, 2x occupancy).
//                        A reg-staged fp32->cvt_pk->1 linear ds_write_b128;
//                        B via global_load_lds fragment-major (2/wave/step).
//  3) attn_kernel      : transposed-S flash attention (R7 LDS staging + R8 (256,2);
//                        unchanged).
//  4) out_kernel       : O @ Wo + bo (R11 asm-read counted template; unchanged).
// Workspace: 72 MiB total (offsets below, unchanged).

#define DM    1024
#define NSEQ  2048
#define HEADS 16
#define HD    64

typedef float floatx4 __attribute__((ext_vector_type(4)));
typedef short s16x4   __attribute__((ext_vector_type(4)));
typedef short s16x8   __attribute__((ext_vector_type(8)));
typedef unsigned int u32x4 __attribute__((ext_vector_type(4)));

static __device__ __forceinline__ floatx4 mfma_bf16(s16x8 a, s16x8 b, floatx4 c) {
  return __builtin_amdgcn_mfma_f32_16x16x32_bf16(a, b, c, 0, 0, 0);
}

// Async global->LDS DMA, 16B per lane: dest = wave-uniform base + lane*16,
// source = per-lane global address.
static __device__ __forceinline__ void gload_lds16(const void* g, void* l) {
  __builtin_amdgcn_global_load_lds(
      (const __attribute__((address_space(1))) unsigned*)g,
      (__attribute__((address_space(3))) unsigned*)l, 16, 0, 0);
}

// 32-bit LDS byte address from a generic pointer into __shared__.
static __device__ __forceinline__ unsigned lds_addr(const void* p) {
  return (unsigned)(unsigned long long)p;
}

// Inline-asm ds_read_b128 (opaque to alias analysis; caller fences per rule #18).
static __device__ __forceinline__ s16x8 ds_read_b128a(unsigned byteaddr) {
  s16x8 r;
  asm volatile("ds_read_b128 %0, %1" : "=v"(r) : "v"(byteaddr));
  return r;
}

#define WAIT_LGKM0() \
  { asm volatile("s_waitcnt lgkmcnt(0)" ::: "memory"); __builtin_amdgcn_sched_barrier(0); }
#define WAIT_VMCNT(N) asm volatile("s_waitcnt vmcnt(" #N ")" ::: "memory")

// fp32 -> bf16 round-to-nearest-even (bit trick; inputs are finite)
static __device__ __forceinline__ short f2bf(float f) {
  unsigned u = __builtin_bit_cast(unsigned, f);
  u += 0x7FFFu + ((u >> 16) & 1u);
  return (short)(u >> 16);
}

// Packed fp32 pair -> 2 bf16 (RNE, same result as f2bf) in one VALU op.
static __device__ __forceinline__ unsigned cvtpk_bf16(float lo, float hi) {
  unsigned r;
  asm("v_cvt_pk_bf16_f32 %0, %1, %2" : "=v"(r) : "v"(lo), "v"(hi));
  return r;
}

// Pack 2 fp32 -> 2 bf16 in one u32 (round-half-up: +0x8000, keep high halves).
static __device__ __forceinline__ unsigned pack2_bf16(float a, float b) {
  unsigned ua = __builtin_bit_cast(unsigned, a) + 0x8000u;
  unsigned ub = __builtin_bit_cast(unsigned, b) + 0x8000u;
#if __has_builtin(__builtin_amdgcn_perm)
  return __builtin_amdgcn_perm(ub, ua, 0x07060302u);  // lo=hi16(ua), hi=hi16(ub)
#else
  return (ub & 0xffff0000u) | (ua >> 16);
#endif
}

// ---------------------------------------------------------------------------
// 1) Weight transpose + cast: W [1024 k][1024 n] fp32 -> Wt [n][k] bf16
__global__ __launch_bounds__(256) void transpose_cast_w(
    const float* __restrict__ W0, const float* __restrict__ W1,
    const float* __restrict__ W2, const float* __restrict__ W3,
    short* __restrict__ T0, short* __restrict__ T1,
    short* __restrict__ T2, short* __restrict__ T3) {
  __shared__ float tile[32][33];
  const float* W = blockIdx.z == 0 ? W0 : blockIdx.z == 1 ? W1 : blockIdx.z == 2 ? W2 : W3;
  short*       T = blockIdx.z == 0 ? T0 : blockIdx.z == 1 ? T1 : blockIdx.z == 2 ? T2 : T3;
  const int bx = blockIdx.x * 32;  // n-offset
  const int by = blockIdx.y * 32;  // k-offset
  const int tx = threadIdx.x, ty = threadIdx.y;
  for (int i = 0; i < 4; i++)
    tile[ty + i * 8][tx] = W[(long)(by + ty + i * 8) * DM + bx + tx];
  __syncthreads();
  for (int i = 0; i < 4; i++)
    T[(long)(bx + ty + i * 8) * DM + by + tx] = f2bf(tile[tx][ty + i * 8]);
}

// ---------------------------------------------------------------------------
// 2) Projection GEMM: C[8192x1024] = A(fp32) @ W.  128x256 tile, 512 threads.
//    Per 24KiB buffer: A bf16, 8 groups x 1KiB at byte g*1024 (group g = rows
//    [row0+g*16,+16), chunk l = row g*16+(l&15), k-cols (l>>4)*8..+8).
//    B bf16, 16 groups x 1KiB at byte 8192 + g*1024 (rows of Bt = C-cols).
//    Producer: wave w reg-stages A group w (lane l: row w*16+lm, 2 float4 at
//    k0+quad*8) -> 4 cvt_pk -> one ds_write_b128 at w*1024+l*16 (linear, 0-conf);
//    B groups 2w,2w+1 via gload_lds. Consumer wave (wm=w>>2, wn=w&3):
//    af[mi]=group wm*4+mi, bfr[ni]=group wn*4+ni, all at group*1KiB+l*16.
//    z=0: queries->Qh (PRE-SCALED log2e/sqrt(1024)), 1: keys->Kh, 2: values->Vt.
__global__ __launch_bounds__(512, 4) void proj_kernel(
    const float* __restrict__ Aq, const float* __restrict__ Ak, const float* __restrict__ Av,
    const short* __restrict__ BtQ, const short* __restrict__ BtK, const short* __restrict__ BtV,
    short* __restrict__ Qh, short* __restrict__ Kh, short* __restrict__ Vt) {
  __shared__ short lds[2 * 12288];  // 2 x 24KiB (A 8KiB + B 16KiB)
  const int z = blockIdx.z;
  const float* A  = z == 0 ? Aq  : z == 1 ? Ak  : Av;
  const short* Bt = z == 0 ? BtQ : z == 1 ? BtK : BtV;
  const int t = threadIdx.x;
  const int w = t >> 6, l = t & 63, quad = l >> 4, lm = l & 15;
  const int wm = w >> 2, wn = w & 3;           // 2 row-waves x 4 col-waves
  const int row0 = blockIdx.x * 128, col0 = blockIdx.y * 256;

  floatx4 acc[4][4];
  for (int mi = 0; mi < 4; mi++)
    for (int ni = 0; ni < 4; ni++) acc[mi][ni] = (floatx4){0.f, 0.f, 0.f, 0.f};

  floatx4 a0, a1;  // A reg-stage: wave w owns A-group w (16 rows x 32 k)
  auto loadA = [&](int k0) __attribute__((always_inline)) {
    const float* p = A + (long)(row0 + w * 16 + lm) * DM + k0 + quad * 8;
    a0 = *(const floatx4*)p;
    a1 = *(const floatx4*)(p + 4);
  };
  auto writeA = [&](int buf) __attribute__((always_inline)) {
    u32x4 pk = {cvtpk_bf16(a0[0], a0[1]), cvtpk_bf16(a0[2], a0[3]),
                cvtpk_bf16(a1[0], a1[1]), cvtpk_bf16(a1[2], a1[3])};
    *(s16x8*)(lds + buf * 12288 + w * 512 + l * 8) = __builtin_bit_cast(s16x8, pk);
  };
  auto stageB = [&](int k0, int buf) __attribute__((always_inline)) {
    short* base = lds + buf * 12288 + 4096;  // B region (byte 8192)
#pragma unroll
    for (int i = 0; i < 2; i++) {
      int g = w * 2 + i;
      const short* src = Bt + (long)(col0 + g * 16 + lm) * DM + k0 + quad * 8;
      gload_lds16(src, base + g * 512);
    }
  };
  auto process = [&](int buf) __attribute__((always_inline)) {
    const short* base = lds + buf * 12288;
    s16x8 af[4], bfr[4];
#pragma unroll
    for (int mi = 0; mi < 4; mi++)
      af[mi] = *(const s16x8*)(base + (wm * 4 + mi) * 512 + l * 8);
#pragma unroll
    for (int ni = 0; ni < 4; ni++)
      bfr[ni] = *(const s16x8*)(base + 4096 + (wn * 4 + ni) * 512 + l * 8);
    __builtin_amdgcn_s_setprio(1);
#pragma unroll
    for (int mi = 0; mi < 4; mi++)
#pragma unroll
      for (int ni = 0; ni < 4; ni++)
        acc[mi][ni] = mfma_bf16(af[mi], bfr[ni], acc[mi][ni]);
    __builtin_amdgcn_s_setprio(0);
  };

  loadA(0);
  stageB(0, 0);
  writeA(0);
  __syncthreads();
  int cur = 0;
  for (int k0 = 0; k0 < DM; k0 += 32) {
    const int kn = (k0 + 32 < DM) ? k0 + 32 : 0;  // uniform clamp (safe addr)
    loadA(kn);           // issue next A loads (land under process)
    stageB(kn, cur ^ 1); // DMA next B
    process(cur);
    writeA(cur ^ 1);     // regs arrived; buf^1 was fully read before last barrier
    __syncthreads();
    cur ^= 1;
  }

  const int rowbase = row0 + wm * 64;  // multiple of 64 -> single b per wave
  const int colbase = col0 + wn * 64;  // multiple of 64 -> single head per wave
  const int b = rowbase >> 11;
  const int h = colbase >> 6;
  const int rloc = rowbase & 2047;
  if (z < 2) {
    short* Out = z == 0 ? Qh : Kh;
    // Fold softmax scale * log2(e) into Q so attn uses exp2 with no multiply.
    const float osc = z == 0 ? 0.0450842200277801f : 1.0f;
    long base = ((long)(b * HEADS + h)) * NSEQ * HD;
    for (int mi = 0; mi < 4; mi++)
      for (int r = 0; r < 4; r++) {
        int q = rloc + mi * 16 + quad * 4 + r;
        long rowoff = base + (long)q * HD + lm;
        for (int ni = 0; ni < 4; ni++)
          Out[rowoff + ni * 16] = f2bf(acc[mi][ni][r] * osc);
      }
  } else {
    // Vt with per-32-key interleave: key kloc=(j*16+quad*4+r) within its 32-group
    // is stored at position quad*8 + j*4 + r, so attn reads one 16B chunk per
    // (d-row, quad) covering a full K=32 logical-k fragment.
    long base = ((long)(b * HEADS + h)) * HD * NSEQ;
    for (int mi = 0; mi < 4; mi++)
      for (int r = 0; r < 4; r++) {
        int kcol = rloc + (mi >> 1) * 32 + quad * 8 + (mi & 1) * 4 + r;
        for (int ni = 0; ni < 4; ni++)
          Vt[base + (long)(ni * 16 + lm) * NSEQ + kcol] = f2bf(acc[mi][ni][r]);
      }
  }
}

// ---------------------------------------------------------------------------
// 3) Transposed-S flash attention. Grid (bh=64, qy=16) -> XCD = bh%8 (L2 local).
//    4 waves/block, wave = 32 q-rows (2x16); K/V tile (64 keys) staged ONCE per
//    block in LDS, fragment-major (16 groups x 1KiB), global_load_lds, double-
//    buffered T3 2-phase. (256,2): 256-VGPR class, no spill (R8). Unchanged.
__global__ __launch_bounds__(256, 2) void attn_kernel(
    const short* __restrict__ Qh, const short* __restrict__ Kh,
    const short* __restrict__ Vt, short* __restrict__ Obf) {
  __shared__ short lds[2 * 8192];  // 2 x 16KiB tile buffers; epilogue reuses buf0
  const int t = threadIdx.x;
  const int w = t >> 6, l = t & 63, quad = l >> 4, lm = l & 15;
  const int bh = blockIdx.x;    // b*16+h  (grid-x => XCD = bh%8: L2 locality)
  const int qtile = blockIdx.y * 128 + w * 32;
  const short* Qp = Qh + (long)bh * NSEQ * HD;
  const short* Kp = Kh + (long)bh * NSEQ * HD;
  const short* Vp = Vt + (long)bh * HD * NSEQ;

  s16x8 aq[2][2];  // Q-frags; serve as MFMA *B* operand for S^T (layout identical)
#pragma unroll
  for (int qi = 0; qi < 2; qi++)
#pragma unroll
    for (int c = 0; c < 2; c++)
      aq[qi][c] = *(const s16x8*)(Qp + (long)(qtile + qi * 16 + lm) * HD + c * 32 + quad * 8);

  floatx4 acc[2][4];  // O^T, C-layout: d = n*16+quad*4+reg, q = lm
  float lsum[2] = {0.f, 0.f};
#pragma unroll
  for (int qi = 0; qi < 2; qi++)
#pragma unroll
    for (int n = 0; n < 4; n++) acc[qi][n] = (floatx4){0.f, 0.f, 0.f, 0.f};

  // Stage the 64-key tile at kt into buffer `buf`. Wave w stages groups 4w..4w+3.
  auto stage = [&](int kt, int buf) __attribute__((always_inline)) {
    short* base = lds + buf * 8192;
#pragma unroll
    for (int i = 0; i < 4; i++) {
      int g = w * 4 + i;
      const short* src;
      if (w < 2) {  // K groups 0..7
        int s = (g >> 2) & 1, j = (g >> 1) & 1, c = g & 1;
        src = Kp + (long)(kt + s * 32 + j * 16 + lm) * HD + c * 32 + quad * 8;
      } else {      // V groups 8..15
        int gg = g & 7;
        int s = gg >> 2, n = gg & 3;
        src = Vp + (long)(n * 16 + lm) * NSEQ + kt + s * 32 + quad * 8;
      }
      gload_lds16(src, base + g * 512);
    }
  };

  // Process one 32-key subtile (s = 0/1) from tile buffer Lb.
  auto process = [&](const short* Lb, int s) __attribute__((always_inline)) {
    s16x8 bk[2][2];
#pragma unroll
    for (int j = 0; j < 2; j++)
#pragma unroll
      for (int c = 0; c < 2; c++)
        bk[j][c] = *(const s16x8*)(Lb + ((s * 4 + j * 2 + c) * 64 + l) * 8);
    s16x8 vraw[4];
#pragma unroll
    for (int n = 0; n < 4; n++)
      vraw[n] = *(const s16x8*)(Lb + ((8 + s * 4 + n) * 64 + l) * 8);
#pragma unroll
    for (int qi = 0; qi < 2; qi++) {
      floatx4 sT[2];
      sT[0] = (floatx4){0.f, 0.f, 0.f, 0.f};
      sT[1] = (floatx4){0.f, 0.f, 0.f, 0.f};
      __builtin_amdgcn_s_setprio(1);
#pragma unroll
      for (int c = 0; c < 2; c++) {
        sT[0] = mfma_bf16(bk[0][c], aq[qi][c], sT[0]);
        sT[1] = mfma_bf16(bk[1][c], aq[qi][c], sT[1]);
      }
      __builtin_amdgcn_s_setprio(0);
      float p0 = __builtin_amdgcn_exp2f(sT[0][0]);
      float p1 = __builtin_amdgcn_exp2f(sT[0][1]);
      float p2 = __builtin_amdgcn_exp2f(sT[0][2]);
      float p3 = __builtin_amdgcn_exp2f(sT[0][3]);
      float p4 = __builtin_amdgcn_exp2f(sT[1][0]);
      float p5 = __builtin_amdgcn_exp2f(sT[1][1]);
      float p6 = __builtin_amdgcn_exp2f(sT[1][2]);
      float p7 = __builtin_amdgcn_exp2f(sT[1][3]);
      lsum[qi] += ((p0 + p1) + (p2 + p3)) + ((p4 + p5) + (p6 + p7));
      u32x4 pw = {pack2_bf16(p0, p1), pack2_bf16(p2, p3),
                  pack2_bf16(p4, p5), pack2_bf16(p6, p7)};
      s16x8 pcat = __builtin_bit_cast(s16x8, pw);
      __builtin_amdgcn_s_setprio(1);
#pragma unroll
      for (int n = 0; n < 4; n++)
        acc[qi][n] = mfma_bf16(vraw[n], pcat, acc[qi][n]);
      __builtin_amdgcn_s_setprio(0);
    }
  };

  stage(0, 0);
  __syncthreads();  // compiler-emitted vmcnt(0) drain + s_barrier: tile 0 ready
  int cur = 0;
  for (int kt = 0; kt < NSEQ; kt += 64) {
    if (kt + 64 < NSEQ) stage(kt + 64, cur ^ 1);  // issue DMA, then compute
    const short* Lb = lds + cur * 8192;
    process(Lb, 0);
    process(Lb, 1);
    __syncthreads();  // drain (hidden under process) + cross-wave visibility
    cur ^= 1;
  }

  // lsum is per-lane over this lane's keys; full row sum = reduce across quads.
  const int b = bh >> 4, h = bh & 15;
  short* Ow = lds + w * 1152;  // reuse buf0 (final iter read buf1; regions disjoint)
  const int erow = l >> 2, ecg = l & 3;  // epilogue read/store mapping
#pragma unroll
  for (int qi = 0; qi < 2; qi++) {
    float ls = lsum[qi];
    ls += __shfl_xor(ls, 16);
    ls += __shfl_xor(ls, 32);
    float rl = 1.0f / ls;  // row sum for q = lm (same for all regs)
#pragma unroll
    for (int n = 0; n < 4; n++)
#pragma unroll
      for (int r = 0; r < 4; r++)
        Ow[lm * 72 + n * 16 + quad * 4 + r] = f2bf(acc[qi][n][r] * rl);
    // read back row-major (same wave; compiler inserts lgkmcnt wait), store coalesced
    s16x8 o0 = *(const s16x8*)(Ow + erow * 72 + ecg * 16);
    s16x8 o1 = *(const s16x8*)(Ow + erow * 72 + ecg * 16 + 8);
    long gaddr = ((long)(b * NSEQ + qtile + qi * 16 + erow)) * DM + h * HD + ecg * 16;
    *(s16x8*)(Obf + gaddr) = o0;
    *(s16x8*)(Obf + gaddr + 8) = o1;
  }
}

// ---------------------------------------------------------------------------
// 4) Output GEMM: d_out = Obf(bf16) @ WoT + bo, fp32 out.
//    R11 asm-read counted-vmcnt 3-buffer template (S=4 -> vmcnt(4)); unchanged.
__global__ __launch_bounds__(256, 2) void out_kernel(
    const short* __restrict__ Ab, const short* __restrict__ Bt,
    const float* __restrict__ bias, float* __restrict__ Out) {
  __shared__ short lds[3 * 8192];
  const int t = threadIdx.x;
  const int w = t >> 6, l = t & 63, quad = l >> 4, lm = l & 15;
  const int wm = w >> 1, wn = w & 1;
  const int row0 = blockIdx.x * 128, col0 = blockIdx.y * 128;

  floatx4 acc[4][4];
  for (int mi = 0; mi < 4; mi++)
    for (int ni = 0; ni < 4; ni++) acc[mi][ni] = (floatx4){0.f, 0.f, 0.f, 0.f};

  auto stage = [&](int k0, int buf) __attribute__((always_inline)) {
    short* base = lds + buf * 8192;
#pragma unroll
    for (int i = 0; i < 4; i++) {
      int g = w * 4 + i;  // 0..15; wave-uniform branch
      const short* src = (g < 8)
          ? Ab + (long)(row0 + g * 16 + lm) * DM + k0 + quad * 8
          : Bt + (long)(col0 + (g - 8) * 16 + lm) * DM + k0 + quad * 8;
      gload_lds16(src, base + g * 512);
    }
  };
  const unsigned lds0 = lds_addr(lds);
  auto process = [&](int buf) __attribute__((always_inline)) {
    const unsigned lbase = lds0 + buf * 16384;
    const unsigned abase = lbase + wm * 4096 + l * 16;
    const unsigned bbase = lbase + 8192 + wn * 4096 + l * 16;
    s16x8 af[4], bfr[4];
#pragma unroll
    for (int mi = 0; mi < 4; mi++)
      af[mi] = ds_read_b128a(abase + mi * 1024);
#pragma unroll
    for (int ni = 0; ni < 4; ni++)
      bfr[ni] = ds_read_b128a(bbase + ni * 1024);
    WAIT_LGKM0();
    __builtin_amdgcn_s_setprio(1);
#pragma unroll
    for (int mi = 0; mi < 4; mi++)
#pragma unroll
      for (int ni = 0; ni < 4; ni++)
        acc[mi][ni] = mfma_bf16(af[mi], bfr[ni], acc[mi][ni]);
    __builtin_amdgcn_s_setprio(0);
  };

  stage(0, 0);
  stage(32, 1);
  int cur = 0;
  for (int tt = 0; tt < 30; ++tt) {
    WAIT_VMCNT(4);
    __builtin_amdgcn_s_barrier();
    __builtin_amdgcn_sched_barrier(0);
    int nb = cur + 2 >= 3 ? cur - 1 : cur + 2;
    stage((tt + 2) * 32, nb);
    __builtin_amdgcn_sched_barrier(0);
    process(cur);
    cur = cur + 1 >= 3 ? 0 : cur + 1;
  }
  WAIT_VMCNT(4);
  __builtin_amdgcn_s_barrier();
  __builtin_amdgcn_sched_barrier(0);
  process(cur);
  cur = cur + 1 >= 3 ? 0 : cur + 1;
  WAIT_VMCNT(0);
  __builtin_amdgcn_s_barrier();
  __builtin_amdgcn_sched_barrier(0);
  process(cur);

  const int rowbase = row0 + wm * 64;
  const int colbase = col0 + wn * 64;
  for (int mi = 0; mi < 4; mi++)
    for (int r = 0; r < 4; r++) {
      int gr = rowbase + mi * 16 + quad * 4 + r;
      for (int ni = 0; ni < 4; ni++) {
        int gc = colbase + ni * 16 + lm;
        Out[(long)gr * DM + gc] = acc[mi][ni][r] + bias[gc];
      }
    }
}

// ---------------------------------------------------------------------------
extern "C" void kernel_launch(void* const* d_in, const int* in_sizes, int n_in,
                              void* d_out, int out_size, void* d_ws, size_t ws_size,
                              hipStream_t stream) {
  (void)in_sizes; (void)n_in; (void)out_size; (void)ws_size;
  const float* queries = (const float*)d_in[0];
  const float* keys    = (const float*)d_in[1];
  const float* values  = (const float*)d_in[2];
  const float* Wq = (const float*)d_in[3];
  const float* Wk = (const float*)d_in[4];
  const float* Wv = (const float*)d_in[5];
  const float* Wo = (const float*)d_in[6];
  const float* bo = (const float*)d_in[7];
  float* out = (float*)d_out;

  char* ws = (char*)d_ws;
  const size_t MB = 1024 * 1024;
  short* WqT = (short*)(ws + 0 * MB);   // 2 MiB each
  short* WkT = (short*)(ws + 2 * MB);
  short* WvT = (short*)(ws + 4 * MB);
  short* WoT = (short*)(ws + 6 * MB);
  short* Qh  = (short*)(ws + 8 * MB);   // [B,H,2048,64] bf16 = 16 MiB
  short* Kh  = (short*)(ws + 24 * MB);  // 16 MiB
  short* Vt  = (short*)(ws + 40 * MB);  // [B,H,64,2048] bf16 (interleaved cols) = 16 MiB
  short* Obf = (short*)(ws + 56 * MB);  // [8192,1024] bf16 = 16 MiB  (total 72 MiB)

  transpose_cast_w<<<dim3(32, 32, 4), dim3(32, 8), 0, stream>>>(
      Wq, Wk, Wv, Wo, WqT, WkT, WvT, WoT);
  proj_kernel<<<dim3(64, 4, 3), 512, 0, stream>>>(
      queries, keys, values, WqT, WkT, WvT, Qh, Kh, Vt);
  attn_kernel<<<dim3(64, 16), 256, 0, stream>>>(Qh, Kh, Vt, Obf);
  out_kernel<<<dim3(64, 8), 256, 0, stream>>>(Obf, WoT, bo, out);
}